// Round 17
// baseline (521.854 us; speedup 1.0000x reference)
//
#include <hip/hip_runtime.h>
#include <hip/hip_bf16.h>

// ---------------- problem constants ----------------
#define BB    64
#define DIMN  256
#define NSLOT 8
#define NTOKN 1024
#define NSTEP 6
#define SCALEF 0.0625f

typedef __attribute__((ext_vector_type(8))) short short8;
typedef __attribute__((ext_vector_type(8))) unsigned short ushort8;
typedef __attribute__((ext_vector_type(4))) unsigned short ushort4v;
typedef __attribute__((ext_vector_type(4))) float f32x4;

__device__ __forceinline__ float b2f(unsigned short u) {
  return __uint_as_float((unsigned)u << 16);
}
__device__ __forceinline__ unsigned short f2b(float f) {
  unsigned u = __float_as_uint(f);
  return (unsigned short)((u + 0x7FFFu + ((u >> 16) & 1u)) >> 16);
}

// conversion table: inputs 1..31
constexpr int kNConv = 31;
constexpr int kConvSizes[kNConv] = {
  131072, 1024, 256, 262144, 262144, 65536, 256, 65536, 256, 256, 256,
  65536, 256, 65536, 256, 65536, 256, 196608, 196608, 768, 768,
  256, 256, 256, 256, 65536, 256, 65536, 256, 256, 256
};
constexpr int kConvTotal = 1513984;

struct PtrPack { const void* p[kNConv]; };

__device__ __forceinline__ float ldin(const void* p, long i, int isbf) {
  if (isbf) return b2f(((const unsigned short*)p)[i]);
  return ((const float*)p)[i];
}

__global__ void detect_dtype(const void* gin, int* flag) {
  unsigned u = *(const unsigned*)gin;
  *flag = (u == 0x3F803F80u) ? 1 : 0;
}

__global__ __launch_bounds__(256) void convert_weights(PtrPack pk, const int* __restrict__ flag,
                                                       float* __restrict__ dst) {
  int idx = blockIdx.x * 256 + threadIdx.x;
  if (idx >= kConvTotal) return;
  int off = idx, a = 0;
  while (a < kNConv - 1 && off >= kConvSizes[a]) { off -= kConvSizes[a]; ++a; }
  dst[idx] = ldin(pk.p[a], off, *flag);
}

// bf16 copies of the 9 GEMM weight matrices
constexpr int kWN = 9;
constexpr int kWSize[kWN]  = {65536, 65536, 65536, 65536, 65536, 196608, 196608, 65536, 65536};
constexpr int kWSrc[kWN]   = {656640, 722432, 788736, 854528, 920320, 986112, 1182720, 1381888, 1447680};
constexpr int kWTotal = 851968;

__global__ __launch_bounds__(256) void convert_wbf16(const float* __restrict__ conv,
                                                     unsigned short* __restrict__ wbf) {
  int idx = blockIdx.x * 256 + threadIdx.x;
  if (idx >= kWTotal) return;
  int off = idx, m = 0;
  while (m < kWN - 1 && off >= kWSize[m]) { off -= kWSize[m]; ++m; }
  wbf[idx] = f2b(conv[kWSrc[m] + off]);
}

// ---------------- encoder: pos-embed + transpose (bf16 out) + batch stats, vectorized ----------------
__global__ __launch_bounds__(256) void posembed_stats(
    const void* __restrict__ in0, const int* __restrict__ flag,
    const float* __restrict__ Wpos, const float* __restrict__ bpos,
    unsigned short* __restrict__ A, float* __restrict__ partials) {
  __shared__ float lds[64 * 65];
  __shared__ float red[8];
  const int tb = blockIdx.x, b = blockIdx.y, tid = threadIdx.x;
  const int t0 = tb * 64;
  const int isbf = *flag;
  float sum = 0.f, ss = 0.f;
  const int tg = tid & 7;
  const int dbase = tid >> 3;
  const int tloc = tg * 8;
  const int dq = tid & 15;
  const int trow = tid >> 4;
  for (int d0 = 0; d0 < DIMN; d0 += 64) {
    __syncthreads();
#pragma unroll
    for (int p = 0; p < 2; ++p) {
      int dd = dbase + p * 32;
      int d = d0 + dd;
      const float* wp = Wpos + d * 4;
      int tf = t0 + tloc;
      float gi = (float)(tf >> 5) * (1.f / 31.f);
      float gj0 = (float)(tf & 31) * (1.f / 31.f);
      float base = wp[0] * gi + wp[2] * (1.f - gi) + wp[1] * gj0 + wp[3] * (1.f - gj0) + bpos[d];
      float step = (wp[1] - wp[3]) * (1.f / 31.f);
      long gidx = ((long)b * DIMN + d) * NTOKN + tf;
      float v[8];
      if (isbf) {
        ushort8 raw = *(const ushort8*)((const unsigned short*)in0 + gidx);
#pragma unroll
        for (int j = 0; j < 8; ++j) v[j] = b2f(raw[j]);
      } else {
        const float* fp = (const float*)in0 + gidx;
        float4 a0 = *(const float4*)fp;
        float4 a1 = *(const float4*)(fp + 4);
        v[0] = a0.x; v[1] = a0.y; v[2] = a0.z; v[3] = a0.w;
        v[4] = a1.x; v[5] = a1.y; v[6] = a1.z; v[7] = a1.w;
      }
#pragma unroll
      for (int j = 0; j < 8; ++j) {
        float val = v[j] + base + step * (float)j;
        sum += val; ss += val * val;
        lds[dd * 65 + tloc + j] = val;
      }
    }
    __syncthreads();
#pragma unroll
    for (int p = 0; p < 4; ++p) {
      int tt = trow + p * 16;
      int dcol = dq * 4;
      ushort4v y;
      y[0] = f2b(lds[(dcol + 0) * 65 + tt]);
      y[1] = f2b(lds[(dcol + 1) * 65 + tt]);
      y[2] = f2b(lds[(dcol + 2) * 65 + tt]);
      y[3] = f2b(lds[(dcol + 3) * 65 + tt]);
      *(ushort4v*)(A + ((long)b * NTOKN + t0 + tt) * DIMN + d0 + dcol) = y;
    }
  }
  for (int off = 32; off; off >>= 1) { sum += __shfl_xor(sum, off); ss += __shfl_xor(ss, off); }
  int w = tid >> 6;
  if ((tid & 63) == 0) { red[w] = sum; red[4 + w] = ss; }
  __syncthreads();
  if (tid == 0) {
    partials[((long)b * 16 + tb) * 2]     = red[0] + red[1] + red[2] + red[3];
    partials[((long)b * 16 + tb) * 2 + 1] = red[4] + red[5] + red[6] + red[7];
  }
}

__global__ void stats_reduce(const float* __restrict__ partials, float* __restrict__ stats) {
  int b = threadIdx.x;
  if (b >= BB) return;
  float s = 0.f, q = 0.f;
  for (int i = 0; i < 16; ++i) {
    s += partials[((long)b * 16 + i) * 2];
    q += partials[((long)b * 16 + i) * 2 + 1];
  }
  const float invN = 1.f / (float)(NTOKN * DIMN);
  float m = s * invN;
  float var = q * invN - m * m;
  stats[b * 2] = m;
  stats[b * 2 + 1] = rsqrtf(var + 1e-5f);
}

// ---------------- gemm_m1ln: 128x128 tile, 512 thr, LN2 fused into As staging, relu, bf16 out ----------------
__global__ __launch_bounds__(512) void gemm_m1ln(
    const unsigned short* __restrict__ X, const float* __restrict__ stats,
    const float* __restrict__ genc, const float* __restrict__ benc,
    const unsigned short* __restrict__ W, const float* __restrict__ bias,
    unsigned short* __restrict__ Y) {
  __shared__ unsigned short As[128 * 264];
  __shared__ unsigned short Bs[128 * 264];
  const int tid = threadIdx.x;
  const long m0 = (long)blockIdx.x * 128;
  const int n0 = blockIdx.y * 128;
  const int bb_ = (int)(m0 >> 10);
  const float mm = stats[bb_ * 2], inv = stats[bb_ * 2 + 1];
#pragma unroll
  for (int i = 0; i < 8; ++i) {
    int c = tid + i * 512;
    int row = c >> 5, seg = c & 31;
    long grow = m0 + row;
    int t = (int)(grow & 1023);
    ushort8 raw = *(const ushort8*)(X + grow * 256 + seg * 8);
    const float* gp = genc + (long)t * 256 + seg * 8;
    const float* bp = benc + (long)t * 256 + seg * 8;
    ushort8 y;
#pragma unroll
    for (int e = 0; e < 8; ++e)
      y[e] = f2b((b2f(raw[e]) - mm) * inv * gp[e] + bp[e]);
    *(ushort8*)&As[row * 264 + seg * 8] = y;
  }
#pragma unroll
  for (int i = 0; i < 8; ++i) {
    int c = tid + i * 512;
    int row = c >> 5, seg = c & 31;
    *(ushort8*)&Bs[row * 264 + seg * 8] = *(const ushort8*)(W + (long)(n0 + row) * 256 + seg * 8);
  }
  __syncthreads();
  const int wave = tid >> 6, lane = tid & 63;
  const int wr = wave >> 1, wc = wave & 1;
  const int lrow = lane & 15, kgrp = lane >> 4;
  f32x4 acc[2][4];
#pragma unroll
  for (int mt = 0; mt < 2; ++mt)
#pragma unroll
    for (int nt = 0; nt < 4; ++nt) acc[mt][nt] = f32x4{0.f, 0.f, 0.f, 0.f};
#pragma unroll
  for (int kc = 0; kc < 8; ++kc) {
    short8 af[2], bf[4];
#pragma unroll
    for (int mt = 0; mt < 2; ++mt)
      af[mt] = *(const short8*)&As[(wr * 32 + mt * 16 + lrow) * 264 + kc * 32 + kgrp * 8];
#pragma unroll
    for (int nt = 0; nt < 4; ++nt)
      bf[nt] = *(const short8*)&Bs[(wc * 64 + nt * 16 + lrow) * 264 + kc * 32 + kgrp * 8];
#pragma unroll
    for (int mt = 0; mt < 2; ++mt)
#pragma unroll
      for (int nt = 0; nt < 4; ++nt)
        acc[mt][nt] = __builtin_amdgcn_mfma_f32_16x16x32_bf16(af[mt], bf[nt], acc[mt][nt], 0, 0, 0);
  }
#pragma unroll
  for (int mt = 0; mt < 2; ++mt)
#pragma unroll
    for (int nt = 0; nt < 4; ++nt) {
      int n = n0 + wc * 64 + nt * 16 + lrow;
      float bn = bias[n];
#pragma unroll
      for (int r = 0; r < 4; ++r) {
        long m = m0 + wr * 32 + mt * 16 + kgrp * 4 + r;
        Y[m * 256 + n] = f2b(fmaxf(acc[mt][nt][r] + bn, 0.f));
      }
    }
}

// ---------------- gemm_tile<ACT,OUT>: 128x128 tile, 512 thr = 8 waves (4x2), K=256 one-shot ----------------
// OUT: 0 = bf16 out; 1 = fp32 out; 2 = fp32 out + fp32 residual
template <int ACT, int OUT>
__global__ __launch_bounds__(512) void gemm_tile(
    const unsigned short* __restrict__ X, const unsigned short* __restrict__ W,
    const float* __restrict__ bias, const float* __restrict__ res,
    void* __restrict__ Y, int Nfull) {
  __shared__ unsigned short As[128 * 264];
  __shared__ unsigned short Bs[128 * 264];
  const int tid = threadIdx.x;
  const long m0 = (long)blockIdx.x * 128;
  const int n0 = blockIdx.y * 128;
#pragma unroll
  for (int i = 0; i < 8; ++i) {
    int c = tid + i * 512;
    int row = c >> 5, seg = c & 31;
    *(ushort8*)&As[row * 264 + seg * 8] = *(const ushort8*)(X + (m0 + row) * 256 + seg * 8);
  }
#pragma unroll
  for (int i = 0; i < 8; ++i) {
    int c = tid + i * 512;
    int row = c >> 5, seg = c & 31;
    *(ushort8*)&Bs[row * 264 + seg * 8] = *(const ushort8*)(W + (long)(n0 + row) * 256 + seg * 8);
  }
  __syncthreads();
  const int wave = tid >> 6, lane = tid & 63;
  const int wr = wave >> 1, wc = wave & 1;
  const int lrow = lane & 15, kgrp = lane >> 4;
  f32x4 acc[2][4];
#pragma unroll
  for (int mt = 0; mt < 2; ++mt)
#pragma unroll
    for (int nt = 0; nt < 4; ++nt) acc[mt][nt] = f32x4{0.f, 0.f, 0.f, 0.f};
#pragma unroll
  for (int kc = 0; kc < 8; ++kc) {
    short8 af[2], bf[4];
#pragma unroll
    for (int mt = 0; mt < 2; ++mt)
      af[mt] = *(const short8*)&As[(wr * 32 + mt * 16 + lrow) * 264 + kc * 32 + kgrp * 8];
#pragma unroll
    for (int nt = 0; nt < 4; ++nt)
      bf[nt] = *(const short8*)&Bs[(wc * 64 + nt * 16 + lrow) * 264 + kc * 32 + kgrp * 8];
#pragma unroll
    for (int mt = 0; mt < 2; ++mt)
#pragma unroll
      for (int nt = 0; nt < 4; ++nt)
        acc[mt][nt] = __builtin_amdgcn_mfma_f32_16x16x32_bf16(af[mt], bf[nt], acc[mt][nt], 0, 0, 0);
  }
#pragma unroll
  for (int mt = 0; mt < 2; ++mt)
#pragma unroll
    for (int nt = 0; nt < 4; ++nt) {
      int n = n0 + wc * 64 + nt * 16 + lrow;
      float bn = bias[n];
#pragma unroll
      for (int r = 0; r < 4; ++r) {
        long m = m0 + wr * 32 + mt * 16 + kgrp * 4 + r;
        float v = acc[mt][nt][r] + bn;
        if (ACT) v = fmaxf(v, 0.f);
        if (OUT == 0)      ((unsigned short*)Y)[m * Nfull + n] = f2b(v);
        else if (OUT == 1) ((float*)Y)[m * Nfull + n] = v;
        else               ((float*)Y)[m * Nfull + n] = v + res[m * Nfull + n];
      }
    }
}

// ---------------- gemm_kv_tile: 512 thr, rowLN fused into A staging, K then V (Bs restaged) ----------------
__global__ __launch_bounds__(512) void gemm_kv_tile(
    const unsigned short* __restrict__ X,
    const float* __restrict__ gin, const float* __restrict__ bin,
    const unsigned short* __restrict__ Wk, const unsigned short* __restrict__ Wv,
    const float* __restrict__ bk, const float* __restrict__ bv,
    unsigned short* __restrict__ Kb, unsigned short* __restrict__ Vb) {
  __shared__ unsigned short As[128 * 264];
  __shared__ unsigned short Bs[128 * 264];
  const int tid = threadIdx.x;
  const long m0 = (long)blockIdx.x * 128;
  const int n0 = blockIdx.y * 128;
#pragma unroll
  for (int i = 0; i < 8; ++i) {
    int c = tid + i * 512;
    int row = c >> 5, seg = c & 31;
    ushort8 raw = *(const ushort8*)(X + (m0 + row) * 256 + seg * 8);
    float v[8];
    float s = 0.f, q = 0.f;
#pragma unroll
    for (int e = 0; e < 8; ++e) {
      v[e] = b2f(raw[e]);
      s += v[e]; q += v[e] * v[e];
    }
#pragma unroll
    for (int msk = 1; msk <= 16; msk <<= 1) {
      s += __shfl_xor(s, msk);
      q += __shfl_xor(q, msk);
    }
    float mean = s * (1.f / 256.f);
    float rinv = rsqrtf(q * (1.f / 256.f) - mean * mean + 1e-5f);
    const float* gp = gin + seg * 8;
    const float* bp = bin + seg * 8;
    ushort8 y;
#pragma unroll
    for (int e = 0; e < 8; ++e)
      y[e] = f2b((v[e] - mean) * rinv * gp[e] + bp[e]);
    *(ushort8*)&As[row * 264 + seg * 8] = y;
  }
  const int wave = tid >> 6, lane = tid & 63;
  const int wr = wave >> 1, wc = wave & 1;
  const int lrow = lane & 15, kgrp = lane >> 4;
  for (int which = 0; which < 2; ++which) {
    const unsigned short* W = which ? Wv : Wk;
    const float* bias = which ? bv : bk;
    unsigned short* Y = which ? Vb : Kb;
    if (which) __syncthreads();
#pragma unroll
    for (int i = 0; i < 8; ++i) {
      int c = tid + i * 512;
      int row = c >> 5, seg = c & 31;
      *(ushort8*)&Bs[row * 264 + seg * 8] = *(const ushort8*)(W + (long)(n0 + row) * 256 + seg * 8);
    }
    __syncthreads();
    f32x4 acc[2][4];
#pragma unroll
    for (int mt = 0; mt < 2; ++mt)
#pragma unroll
      for (int nt = 0; nt < 4; ++nt) acc[mt][nt] = f32x4{0.f, 0.f, 0.f, 0.f};
#pragma unroll
    for (int kc = 0; kc < 8; ++kc) {
      short8 af[2], bf[4];
#pragma unroll
      for (int mt = 0; mt < 2; ++mt)
        af[mt] = *(const short8*)&As[(wr * 32 + mt * 16 + lrow) * 264 + kc * 32 + kgrp * 8];
#pragma unroll
      for (int nt = 0; nt < 4; ++nt)
        bf[nt] = *(const short8*)&Bs[(wc * 64 + nt * 16 + lrow) * 264 + kc * 32 + kgrp * 8];
#pragma unroll
      for (int mt = 0; mt < 2; ++mt)
#pragma unroll
        for (int nt = 0; nt < 4; ++nt)
          acc[mt][nt] = __builtin_amdgcn_mfma_f32_16x16x32_bf16(af[mt], bf[nt], acc[mt][nt], 0, 0, 0);
    }
#pragma unroll
    for (int mt = 0; mt < 2; ++mt)
#pragma unroll
      for (int nt = 0; nt < 4; ++nt) {
        int n = n0 + wc * 64 + nt * 16 + lrow;
        float bn = bias[n];
#pragma unroll
        for (int r = 0; r < 4; ++r) {
          long m = m0 + wr * 32 + mt * 16 + kgrp * 4 + r;
          Y[m * 256 + n] = f2b(acc[mt][nt][r] + bn);
        }
      }
  }
}

// ---------------- gemm_tile64<ACT,OUT>: 64x128 tile for small-M GEMMs (256 thr) ----------------
// OUT: 0 = bf16; 1 = fp32; 2 = fp32 + res; 3 = fp32 + res, also bf16 copy to sbout
template <int ACT, int OUT>
__global__ __launch_bounds__(256) void gemm_tile64(
    const unsigned short* __restrict__ X, const unsigned short* __restrict__ W,
    const float* __restrict__ bias, const float* __restrict__ res,
    void* __restrict__ Y, unsigned short* __restrict__ sbout, int Nfull) {
  __shared__ unsigned short As[64 * 264];
  __shared__ unsigned short Bs[128 * 264];
  const int tid = threadIdx.x;
  const long m0 = (long)blockIdx.x * 64;
  const int n0 = blockIdx.y * 128;
#pragma unroll
  for (int i = 0; i < 8; ++i) {
    int c = tid + i * 256;
    int row = c >> 5, seg = c & 31;
    *(ushort8*)&As[row * 264 + seg * 8] = *(const ushort8*)(X + (m0 + row) * 256 + seg * 8);
  }
#pragma unroll
  for (int i = 0; i < 16; ++i) {
    int c = tid + i * 256;
    int row = c >> 5, seg = c & 31;
    *(ushort8*)&Bs[row * 264 + seg * 8] = *(const ushort8*)(W + (long)(n0 + row) * 256 + seg * 8);
  }
  __syncthreads();
  const int wave = tid >> 6, lane = tid & 63;
  const int lrow = lane & 15, kgrp = lane >> 4;
  f32x4 acc[8];
#pragma unroll
  for (int nt = 0; nt < 8; ++nt) acc[nt] = f32x4{0.f, 0.f, 0.f, 0.f};
#pragma unroll
  for (int kc = 0; kc < 8; ++kc) {
    short8 af = *(const short8*)&As[(wave * 16 + lrow) * 264 + kc * 32 + kgrp * 8];
#pragma unroll
    for (int nt = 0; nt < 8; ++nt) {
      short8 bf = *(const short8*)&Bs[(nt * 16 + lrow) * 264 + kc * 32 + kgrp * 8];
      acc[nt] = __builtin_amdgcn_mfma_f32_16x16x32_bf16(af, bf, acc[nt], 0, 0, 0);
    }
  }
#pragma unroll
  for (int nt = 0; nt < 8; ++nt) {
    int n = n0 + nt * 16 + lrow;
    float bn = bias[n];
#pragma unroll
    for (int r = 0; r < 4; ++r) {
      long m = m0 + wave * 16 + kgrp * 4 + r;
      float v = acc[nt][r] + bn;
      if (ACT) v = fmaxf(v, 0.f);
      if (OUT == 0)      ((unsigned short*)Y)[m * Nfull + n] = f2b(v);
      else if (OUT == 1) ((float*)Y)[m * Nfull + n] = v;
      else if (OUT == 2) ((float*)Y)[m * Nfull + n] = v + res[m * Nfull + n];
      else {
        float o = v + res[m * Nfull + n];
        ((float*)Y)[m * Nfull + n] = o;
        sbout[m * Nfull + n] = f2b(o);
      }
    }
  }
}

// ---------------- gigh_tile: 512 thr, 128x128 tile, z selects gi/gh, fp32 out stride 768 ----------------
__global__ __launch_bounds__(512) void gigh_tile(
    const unsigned short* __restrict__ updb, const unsigned short* __restrict__ sbf,
    const unsigned short* __restrict__ Wih, const unsigned short* __restrict__ Whh,
    const float* __restrict__ bih, const float* __restrict__ bhh,
    float* __restrict__ gib, float* __restrict__ ghb) {
  const unsigned short* X = blockIdx.z ? sbf : updb;
  const unsigned short* W = blockIdx.z ? Whh : Wih;
  const float* bias = blockIdx.z ? bhh : bih;
  float* Y = blockIdx.z ? ghb : gib;
  __shared__ unsigned short As[128 * 264];
  __shared__ unsigned short Bs[128 * 264];
  const int tid = threadIdx.x;
  const long m0 = (long)blockIdx.x * 128;
  const int n0 = blockIdx.y * 128;
#pragma unroll
  for (int i = 0; i < 8; ++i) {
    int c = tid + i * 512;
    int row = c >> 5, seg = c & 31;
    *(ushort8*)&As[row * 264 + seg * 8] = *(const ushort8*)(X + (m0 + row) * 256 + seg * 8);
  }
#pragma unroll
  for (int i = 0; i < 8; ++i) {
    int c = tid + i * 512;
    int row = c >> 5, seg = c & 31;
    *(ushort8*)&Bs[row * 264 + seg * 8] = *(const ushort8*)(W + (long)(n0 + row) * 256 + seg * 8);
  }
  __syncthreads();
  const int wave = tid >> 6, lane = tid & 63;
  const int wr = wave >> 1, wc = wave & 1;
  const int lrow = lane & 15, kgrp = lane >> 4;
  f32x4 acc[2][4];
#pragma unroll
  for (int mt = 0; mt < 2; ++mt)
#pragma unroll
    for (int nt = 0; nt < 4; ++nt) acc[mt][nt] = f32x4{0.f, 0.f, 0.f, 0.f};
#pragma unroll
  for (int kc = 0; kc < 8; ++kc) {
    short8 af[2], bf[4];
#pragma unroll
    for (int mt = 0; mt < 2; ++mt)
      af[mt] = *(const short8*)&As[(wr * 32 + mt * 16 + lrow) * 264 + kc * 32 + kgrp * 8];
#pragma unroll
    for (int nt = 0; nt < 4; ++nt)
      bf[nt] = *(const short8*)&Bs[(wc * 64 + nt * 16 + lrow) * 264 + kc * 32 + kgrp * 8];
#pragma unroll
    for (int mt = 0; mt < 2; ++mt)
#pragma unroll
      for (int nt = 0; nt < 4; ++nt)
        acc[mt][nt] = __builtin_amdgcn_mfma_f32_16x16x32_bf16(af[mt], bf[nt], acc[mt][nt], 0, 0, 0);
  }
#pragma unroll
  for (int mt = 0; mt < 2; ++mt)
#pragma unroll
    for (int nt = 0; nt < 4; ++nt) {
      int n = n0 + wc * 64 + nt * 16 + lrow;
      float bn = bias[n];
#pragma unroll
      for (int r = 0; r < 4; ++r) {
        long m = m0 + wr * 32 + mt * 16 + kgrp * 4 + r;
        Y[m * 768 + n] = acc[mt][nt][r] + bn;
      }
    }
}

// ---------------- slots init (fp32 + bf16 copy) ----------------
__global__ __launch_bounds__(256) void slots_init(const float* __restrict__ noise, const float* __restrict__ mu,
                                                  const float* __restrict__ sigma, float* __restrict__ slots,
                                                  unsigned short* __restrict__ sbf) {
  long i = (long)blockIdx.x * 256 + threadIdx.x;
  int d = (int)(i & 255);
  float v = mu[d] + sigma[d] * noise[i];
  slots[i] = v;
  sbf[i] = f2b(v);
}

// ---------------- attn1b: fused LN(slots)+q GEMM + MFMA dots + softmax + asum/upd partials ----------------
__global__ __launch_bounds__(256) void attn1b(
    const float* __restrict__ slots, const float* __restrict__ gs, const float* __restrict__ bs,
    const unsigned short* __restrict__ Wq, const float* __restrict__ bq,
    const unsigned short* __restrict__ Kb, const unsigned short* __restrict__ Vb,
    unsigned short* __restrict__ upd_part, float* __restrict__ asum_part) {
  __shared__ unsigned short Ks[64 * 264];
  __shared__ unsigned short Qs[16 * 264];
  __shared__ unsigned short S[16 * 264];
  __shared__ float attnS[64 * 8];
  __shared__ float red[4 * 2048];
  const int jt = blockIdx.x, b = blockIdx.y, tid = threadIdx.x;
  const int wave = tid >> 6, lane = tid & 63;
  // stage K tile
#pragma unroll
  for (int i = 0; i < 8; ++i) {
    int c = tid + i * 256;
    int row = c >> 5, seg = c & 31;
    *(ushort8*)&Ks[row * 264 + seg * 8] =
        *(const ushort8*)(Kb + ((long)(b * NTOKN + jt * 64 + row)) * 256 + seg * 8);
  }
  // zero pad rows of S and Qs
  for (int i = tid; i < 8 * 264; i += 256) { S[8 * 264 + i] = 0; Qs[8 * 264 + i] = 0; }
  // LN(slots) rows 0..7 -> S
#pragma unroll
  for (int rr = 0; rr < 2; ++rr) {
    int row = wave * 2 + rr;
    float4 xv = *(const float4*)(slots + ((long)b * 8 + row) * 256 + lane * 4);
    float s = xv.x + xv.y + xv.z + xv.w;
    float q = xv.x * xv.x + xv.y * xv.y + xv.z * xv.z + xv.w * xv.w;
    for (int off = 32; off; off >>= 1) { s += __shfl_xor(s, off); q += __shfl_xor(q, off); }
    float m = s * (1.f / 256.f);
    float inv = rsqrtf(q * (1.f / 256.f) - m * m + 1e-5f);
    float4 gv = *(const float4*)(gs + lane * 4);
    float4 bv = *(const float4*)(bs + lane * 4);
    ushort4v y;
    y[0] = f2b((xv.x - m) * inv * gv.x + bv.x);
    y[1] = f2b((xv.y - m) * inv * gv.y + bv.y);
    y[2] = f2b((xv.z - m) * inv * gv.z + bv.z);
    y[3] = f2b((xv.w - m) * inv * gv.w + bv.w);
    *(ushort4v*)&S[row * 264 + lane * 4] = y;
  }
  __syncthreads();
  const int lrow = lane & 15, kgrp = lane >> 4;
  // q GEMM into Qs (same math as old lnq_q)
  {
    short8 a[8];
#pragma unroll
    for (int kc = 0; kc < 8; ++kc)
      a[kc] = *(const short8*)&S[lrow * 264 + kc * 32 + kgrp * 8];
#pragma unroll
    for (int nt = 0; nt < 4; ++nt) {
      const int n = wave * 64 + nt * 16 + lrow;
      const unsigned short* wp = Wq + (long)n * 256 + kgrp * 8;
      f32x4 acc = {0.f, 0.f, 0.f, 0.f};
#pragma unroll
      for (int kc = 0; kc < 8; ++kc)
        acc = __builtin_amdgcn_mfma_f32_16x16x32_bf16(a[kc], *(const short8*)(wp + kc * 32), acc, 0, 0, 0);
      if (kgrp < 2) {
        float bn = bq[n];
#pragma unroll
        for (int r = 0; r < 4; ++r)
          Qs[(kgrp * 4 + r) * 264 + n] = f2b(acc[r] + bn);
      }
    }
  }
  __syncthreads();
  // dots
  f32x4 acc = {0.f, 0.f, 0.f, 0.f};
#pragma unroll
  for (int kc = 0; kc < 8; ++kc) {
    short8 af = *(const short8*)&Ks[(wave * 16 + lrow) * 264 + kc * 32 + kgrp * 8];
    short8 qf = *(const short8*)&Qs[lrow * 264 + kc * 32 + kgrp * 8];
    acc = __builtin_amdgcn_mfma_f32_16x16x32_bf16(af, qf, acc, 0, 0, 0);
  }
  float t0[4], mx[4], e[4], sm[4];
#pragma unroll
  for (int r = 0; r < 4; ++r) { t0[r] = acc[r] * SCALEF; mx[r] = t0[r]; }
#pragma unroll
  for (int msk = 1; msk <= 4; msk <<= 1)
#pragma unroll
    for (int r = 0; r < 4; ++r) mx[r] = fmaxf(mx[r], __shfl_xor(mx[r], msk));
#pragma unroll
  for (int r = 0; r < 4; ++r) { e[r] = expf(t0[r] - mx[r]); sm[r] = e[r]; }
#pragma unroll
  for (int msk = 1; msk <= 4; msk <<= 1)
#pragma unroll
    for (int r = 0; r < 4; ++r) sm[r] += __shfl_xor(sm[r], msk);
  if (lrow < 8) {
#pragma unroll
    for (int r = 0; r < 4; ++r) {
      int jl = wave * 16 + kgrp * 4 + r;
      attnS[jl * 8 + lrow] = e[r] / sm[r] + 1e-8f;
    }
  }
  __syncthreads();
  {
    int s0 = wave * 2;
    float v0 = attnS[lane * 8 + s0], v1 = attnS[lane * 8 + s0 + 1];
    for (int off = 32; off; off >>= 1) { v0 += __shfl_xor(v0, off); v1 += __shfl_xor(v1, off); }
    if (lane == 0) {
      asum_part[((long)(b * 16 + jt)) * 8 + s0] = v0;
      asum_part[((long)(b * 16 + jt)) * 8 + s0 + 1] = v1;
    }
  }
  float au[8][4] = {};
  for (int jl = 0; jl < 16; ++jl) {
    int j = wave * 16 + jl;
    ushort4v v4 = *(const ushort4v*)(Vb + ((long)(b * NTOKN + jt * 64 + j)) * 256 + lane * 4);
    float v0 = b2f(v4[0]), v1 = b2f(v4[1]), v2 = b2f(v4[2]), v3 = b2f(v4[3]);
    float4 a01 = *(const float4*)&attnS[j * 8];
    float4 a23 = *(const float4*)&attnS[j * 8 + 4];
    float aw[8] = {a01.x, a01.y, a01.z, a01.w, a23.x, a23.y, a23.z, a23.w};
#pragma unroll
    for (int s = 0; s < 8; ++s) {
      au[s][0] += aw[s] * v0; au[s][1] += aw[s] * v1;
      au[s][2] += aw[s] * v2; au[s][3] += aw[s] * v3;
    }
  }
#pragma unroll
  for (int s = 0; s < 8; ++s)
    *(float4*)&red[wave * 2048 + s * 256 + lane * 4] = make_float4(au[s][0], au[s][1], au[s][2], au[s][3]);
  __syncthreads();
#pragma unroll
  for (int i = 0; i < 8; ++i) {
    int idx = tid + i * 256;
    float sum = red[idx] + red[2048 + idx] + red[4096 + idx] + red[6144 + idx];
    upd_part[((long)(b * 16 + jt)) * 2048 + idx] = f2b(sum);
  }
}

// ---------------- upd_reduce (bf16 partials in) ----------------
__global__ __launch_bounds__(256) void upd_reduce(
    const unsigned short* __restrict__ upd_part, const float* __restrict__ asum_part,
    unsigned short* __restrict__ updb) {
  const int bx = blockIdx.x;
  const int b = bx >> 3, s = bx & 7;
  const int tid = threadIdx.x;
  float as = 0.f;
#pragma unroll
  for (int jt = 0; jt < 16; ++jt) as += asum_part[((long)(b * 16 + jt)) * 8 + s];
  float sum = 0.f;
#pragma unroll
  for (int jt = 0; jt < 16; ++jt)
    sum += b2f(upd_part[((long)(b * 16 + jt)) * 2048 + s * 256 + tid]);
  updb[((long)b * 8 + s) * 256 + tid] = f2b(sum / as);
}

// ---------------- GRU gates + LN(g_ff) fused ----------------
__global__ __launch_bounds__(256) void gru_ln(const float* __restrict__ gi, const float* __restrict__ gh,
                                              const float* __restrict__ slots,
                                              const float* __restrict__ gff, const float* __restrict__ bff,
                                              float* __restrict__ ns, unsigned short* __restrict__ ffl) {
  const int tid = threadIdx.x, lane = tid & 63;
  const long row = (long)blockIdx.x * 4 + (tid >> 6);
  const int d = lane * 4;
  float4 i1 = *(const float4*)(gi + row * 768 + d);
  float4 i2 = *(const float4*)(gi + row * 768 + 256 + d);
  float4 i3 = *(const float4*)(gi + row * 768 + 512 + d);
  float4 h1 = *(const float4*)(gh + row * 768 + d);
  float4 h2 = *(const float4*)(gh + row * 768 + 256 + d);
  float4 h3 = *(const float4*)(gh + row * 768 + 512 + d);
  float4 sl = *(const float4*)(slots + row * 256 + d);
  float n4[4];
  float r, z, nn;
  r = 1.f / (1.f + expf(-(i1.x + h1.x))); z = 1.f / (1.f + expf(-(i2.x + h2.x)));
  nn = tanhf(i3.x + r * h3.x); n4[0] = (1.f - z) * nn + z * sl.x;
  r = 1.f / (1.f + expf(-(i1.y + h1.y))); z = 1.f / (1.f + expf(-(i2.y + h2.y)));
  nn = tanhf(i3.y + r * h3.y); n4[1] = (1.f - z) * nn + z * sl.y;
  r = 1.f / (1.f + expf(-(i1.z + h1.z))); z = 1.f / (1.f + expf(-(i2.z + h2.z)));
  nn = tanhf(i3.z + r * h3.z); n4[2] = (1.f - z) * nn + z * sl.z;
  r = 1.f / (1.f + expf(-(i1.w + h1.w))); z = 1.f / (1.f + expf(-(i2.w + h2.w)));
  nn = tanhf(i3.w + r * h3.w); n4[3] = (1.f - z) * nn + z * sl.w;
  *(float4*)(ns + row * 256 + d) = make_float4(n4[0], n4[1], n4[2], n4[3]);
  float s = n4[0] + n4[1] + n4[2] + n4[3];
  float q = n4[0] * n4[0] + n4[1] * n4[1] + n4[2] * n4[2] + n4[3] * n4[3];
  for (int off = 32; off; off >>= 1) { s += __shfl_xor(s, off); q += __shfl_xor(q, off); }
  float m = s * (1.f / 256.f);
  float inv = rsqrtf(q * (1.f / 256.f) - m * m + 1e-5f);
  float4 gv = *(const float4*)(gff + d);
  float4 bv = *(const float4*)(bff + d);
  ushort4v y;
  y[0] = f2b((n4[0] - m) * inv * gv.x + bv.x);
  y[1] = f2b((n4[1] - m) * inv * gv.y + bv.y);
  y[2] = f2b((n4[2] - m) * inv * gv.z + bv.z);
  y[3] = f2b((n4[3] - m) * inv * gv.w + bv.w);
  *(ushort4v*)(ffl + row * 256 + d) = y;
}

// ---------------- output ----------------
__global__ __launch_bounds__(256) void write_out(const float* __restrict__ slots, const int* __restrict__ flag,
                                                 void* __restrict__ out) {
  long i = (long)blockIdx.x * 256 + threadIdx.x;
  float v = slots[i];
  if (*flag) ((__hip_bfloat16*)out)[i] = __float2bfloat16(v);
  else ((float*)out)[i] = v;
}

// ---------------- host ----------------
extern "C" void kernel_launch(void* const* d_in, const int* in_sizes, int n_in,
                              void* d_out, int out_size, void* d_ws, size_t ws_size,
                              hipStream_t stream) {
  (void)in_sizes; (void)n_in; (void)out_size; (void)ws_size;
  float* wsf = (float*)d_ws;
  long o = 0;
  float* conv = wsf; o += kConvTotal;
  unsigned short* wbf = (unsigned short*)(wsf + o); o += kWTotal / 2;
  unsigned short* A   = (unsigned short*)(wsf + o); o += (long)BB * NTOKN * DIMN / 2;
  unsigned short* X1  = (unsigned short*)(wsf + o); o += (long)BB * NTOKN * DIMN / 2;
  unsigned short* X2  = (unsigned short*)(wsf + o); o += (long)BB * NTOKN * DIMN / 2;
  unsigned short* Kb  = (unsigned short*)(wsf + o); o += (long)BB * NTOKN * DIMN / 2;
  unsigned short* Vb  = (unsigned short*)(wsf + o); o += (long)BB * NTOKN * DIMN / 2;
  float* slots = wsf + o; o += 131072;
  unsigned short* sbf = (unsigned short*)(wsf + o); o += 65536;
  unsigned short* upd_part = (unsigned short*)(wsf + o); o += 1048576;  // [64][16][8][256] bf16
  float* asum_part = wsf + o; o += 8192;
  unsigned short* updb = (unsigned short*)(wsf + o); o += 65536;
  float* gib   = wsf + o; o += 393216;
  float* ghb   = wsf + o; o += 393216;
  float* nsb   = wsf + o; o += 131072;
  unsigned short* ffl  = (unsigned short*)(wsf + o); o += 65536;
  unsigned short* hbuf = (unsigned short*)(wsf + o); o += 65536;
  float* partials = wsf + o; o += 2048;
  float* stats = wsf + o; o += 128;
  int* flag = (int*)(wsf + o); o += 16;

  long coff[kNConv];
  { long acc = 0; for (int i = 0; i < kNConv; ++i) { coff[i] = acc; acc += kConvSizes[i]; } }
  const float* noise_f = conv + coff[0];
  const float* Wpos = conv + coff[1];
  const float* bpos = conv + coff[2];
  const float* genc = conv + coff[3];
  const float* benc = conv + coff[4];
  const float* bm1  = conv + coff[6];
  const float* bm2  = conv + coff[8];
  const float* gin  = conv + coff[9];
  const float* bin  = conv + coff[10];
  const float* bq   = conv + coff[12];
  const float* bk   = conv + coff[14];
  const float* bv   = conv + coff[16];
  const float* bih  = conv + coff[19];
  const float* bhh  = conv + coff[20];
  const float* gs   = conv + coff[21];
  const float* bs   = conv + coff[22];
  const float* gff  = conv + coff[23];
  const float* bff  = conv + coff[24];
  const float* bf1  = conv + coff[26];
  const float* bf2  = conv + coff[28];
  const float* mu   = conv + coff[29];
  const float* sigma = conv + coff[30];

  const unsigned short* Wm1b = wbf;
  const unsigned short* Wm2b = wbf + 65536;
  const unsigned short* Wqb  = wbf + 131072;
  const unsigned short* Wkb  = wbf + 196608;
  const unsigned short* Wvb  = wbf + 262144;
  const unsigned short* Wihb = wbf + 327680;
  const unsigned short* Whhb = wbf + 524288;
  const unsigned short* Wf1b = wbf + 720896;
  const unsigned short* Wf2b = wbf + 786432;

  detect_dtype<<<1, 1, 0, stream>>>(d_in[10], flag);

  PtrPack pk;
  for (int i = 0; i < kNConv; ++i) pk.p[i] = d_in[i + 1];
  convert_weights<<<(kConvTotal + 255) / 256, 256, 0, stream>>>(pk, flag, conv);
  convert_wbf16<<<(kWTotal + 255) / 256, 256, 0, stream>>>(conv, wbf);

  // encoder
  posembed_stats<<<dim3(16, 64), 256, 0, stream>>>(d_in[0], flag, Wpos, bpos, A, partials);
  stats_reduce<<<1, 64, 0, stream>>>(partials, stats);
  const int MT = BB * NTOKN / 128;  // 512 m-tiles
  gemm_m1ln<<<dim3(MT, 2), 512, 0, stream>>>(A, stats, genc, benc, Wm1b, bm1, X1);
  gemm_tile<1, 0><<<dim3(MT, 2), 512, 0, stream>>>(X1, Wm2b, bm2, nullptr, X2, 256);
  gemm_kv_tile<<<dim3(MT, 2), 512, 0, stream>>>(X2, gin, bin, Wkb, Wvb, bk, bv, Kb, Vb);

  slots_init<<<512, 256, 0, stream>>>(noise_f, mu, sigma, slots, sbf);

  for (int it = 0; it < NSTEP; ++it) {
    attn1b<<<dim3(16, 64), 256, 0, stream>>>(slots, gs, bs, Wqb, bq, Kb, Vb, upd_part, asum_part);
    upd_reduce<<<512, 256, 0, stream>>>(upd_part, asum_part, updb);
    gigh_tile<<<dim3(4, 6, 2), 512, 0, stream>>>(updb, sbf, Wihb, Whhb, bih, bhh, gib, ghb);
    gru_ln<<<128, 256, 0, stream>>>(gib, ghb, slots, gff, bff, nsb, ffl);
    gemm_tile64<1, 0><<<dim3(8, 2), 256, 0, stream>>>(ffl, Wf1b, bf1, nullptr, hbuf, nullptr, 256);
    gemm_tile64<0, 3><<<dim3(8, 2), 256, 0, stream>>>(hbuf, Wf2b, bf2, nsb, slots, sbf, 256);
  }

  write_out<<<512, 256, 0, stream>>>(slots, flag, d_out);
}

// Round 18
// 401.279 us; speedup vs baseline: 1.3005x; 1.3005x over previous
//
#include <hip/hip_runtime.h>
#include <hip/hip_bf16.h>

// ---------------- problem constants ----------------
#define BB    64
#define DIMN  256
#define NSLOT 8
#define NTOKN 1024
#define NSTEP 6
#define SCALEF 0.0625f

typedef __attribute__((ext_vector_type(8))) short short8;
typedef __attribute__((ext_vector_type(8))) unsigned short ushort8;
typedef __attribute__((ext_vector_type(4))) unsigned short ushort4v;
typedef __attribute__((ext_vector_type(4))) float f32x4;

__device__ __forceinline__ float b2f(unsigned short u) {
  return __uint_as_float((unsigned)u << 16);
}
__device__ __forceinline__ unsigned short f2b(float f) {
  unsigned u = __float_as_uint(f);
  return (unsigned short)((u + 0x7FFFu + ((u >> 16) & 1u)) >> 16);
}

// conversion table: inputs 1..31
constexpr int kNConv = 31;
constexpr int kConvSizes[kNConv] = {
  131072, 1024, 256, 262144, 262144, 65536, 256, 65536, 256, 256, 256,
  65536, 256, 65536, 256, 65536, 256, 196608, 196608, 768, 768,
  256, 256, 256, 256, 65536, 256, 65536, 256, 256, 256
};
constexpr int kConvTotal = 1513984;

struct PtrPack { const void* p[kNConv]; };

__device__ __forceinline__ float ldin(const void* p, long i, int isbf) {
  if (isbf) return b2f(((const unsigned short*)p)[i]);
  return ((const float*)p)[i];
}

__global__ void detect_dtype(const void* gin, int* flag) {
  unsigned u = *(const unsigned*)gin;
  *flag = (u == 0x3F803F80u) ? 1 : 0;
}

__global__ __launch_bounds__(256) void convert_weights(PtrPack pk, const int* __restrict__ flag,
                                                       float* __restrict__ dst) {
  int idx = blockIdx.x * 256 + threadIdx.x;
  if (idx >= kConvTotal) return;
  int off = idx, a = 0;
  while (a < kNConv - 1 && off >= kConvSizes[a]) { off -= kConvSizes[a]; ++a; }
  dst[idx] = ldin(pk.p[a], off, *flag);
}

// bf16 copies of the 9 GEMM weight matrices
constexpr int kWN = 9;
constexpr int kWSize[kWN]  = {65536, 65536, 65536, 65536, 65536, 196608, 196608, 65536, 65536};
constexpr int kWSrc[kWN]   = {656640, 722432, 788736, 854528, 920320, 986112, 1182720, 1381888, 1447680};
constexpr int kWTotal = 851968;

__global__ __launch_bounds__(256) void convert_wbf16(const float* __restrict__ conv,
                                                     unsigned short* __restrict__ wbf) {
  int idx = blockIdx.x * 256 + threadIdx.x;
  if (idx >= kWTotal) return;
  int off = idx, m = 0;
  while (m < kWN - 1 && off >= kWSize[m]) { off -= kWSize[m]; ++m; }
  wbf[idx] = f2b(conv[kWSrc[m] + off]);
}

// ---------------- encoder: pos-embed + transpose (bf16 out) + batch stats, vectorized ----------------
__global__ __launch_bounds__(256) void posembed_stats(
    const void* __restrict__ in0, const int* __restrict__ flag,
    const float* __restrict__ Wpos, const float* __restrict__ bpos,
    unsigned short* __restrict__ A, float* __restrict__ partials) {
  __shared__ float lds[64 * 65];
  __shared__ float red[8];
  const int tb = blockIdx.x, b = blockIdx.y, tid = threadIdx.x;
  const int t0 = tb * 64;
  const int isbf = *flag;
  float sum = 0.f, ss = 0.f;
  const int tg = tid & 7;
  const int dbase = tid >> 3;
  const int tloc = tg * 8;
  const int dq = tid & 15;
  const int trow = tid >> 4;
  for (int d0 = 0; d0 < DIMN; d0 += 64) {
    __syncthreads();
#pragma unroll
    for (int p = 0; p < 2; ++p) {
      int dd = dbase + p * 32;
      int d = d0 + dd;
      const float* wp = Wpos + d * 4;
      int tf = t0 + tloc;
      float gi = (float)(tf >> 5) * (1.f / 31.f);
      float gj0 = (float)(tf & 31) * (1.f / 31.f);
      float base = wp[0] * gi + wp[2] * (1.f - gi) + wp[1] * gj0 + wp[3] * (1.f - gj0) + bpos[d];
      float step = (wp[1] - wp[3]) * (1.f / 31.f);
      long gidx = ((long)b * DIMN + d) * NTOKN + tf;
      float v[8];
      if (isbf) {
        ushort8 raw = *(const ushort8*)((const unsigned short*)in0 + gidx);
#pragma unroll
        for (int j = 0; j < 8; ++j) v[j] = b2f(raw[j]);
      } else {
        const float* fp = (const float*)in0 + gidx;
        float4 a0 = *(const float4*)fp;
        float4 a1 = *(const float4*)(fp + 4);
        v[0] = a0.x; v[1] = a0.y; v[2] = a0.z; v[3] = a0.w;
        v[4] = a1.x; v[5] = a1.y; v[6] = a1.z; v[7] = a1.w;
      }
#pragma unroll
      for (int j = 0; j < 8; ++j) {
        float val = v[j] + base + step * (float)j;
        sum += val; ss += val * val;
        lds[dd * 65 + tloc + j] = val;
      }
    }
    __syncthreads();
#pragma unroll
    for (int p = 0; p < 4; ++p) {
      int tt = trow + p * 16;
      int dcol = dq * 4;
      ushort4v y;
      y[0] = f2b(lds[(dcol + 0) * 65 + tt]);
      y[1] = f2b(lds[(dcol + 1) * 65 + tt]);
      y[2] = f2b(lds[(dcol + 2) * 65 + tt]);
      y[3] = f2b(lds[(dcol + 3) * 65 + tt]);
      *(ushort4v*)(A + ((long)b * NTOKN + t0 + tt) * DIMN + d0 + dcol) = y;
    }
  }
  for (int off = 32; off; off >>= 1) { sum += __shfl_xor(sum, off); ss += __shfl_xor(ss, off); }
  int w = tid >> 6;
  if ((tid & 63) == 0) { red[w] = sum; red[4 + w] = ss; }
  __syncthreads();
  if (tid == 0) {
    partials[((long)b * 16 + tb) * 2]     = red[0] + red[1] + red[2] + red[3];
    partials[((long)b * 16 + tb) * 2 + 1] = red[4] + red[5] + red[6] + red[7];
  }
}

__global__ void stats_reduce(const float* __restrict__ partials, float* __restrict__ stats) {
  int b = threadIdx.x;
  if (b >= BB) return;
  float s = 0.f, q = 0.f;
  for (int i = 0; i < 16; ++i) {
    s += partials[((long)b * 16 + i) * 2];
    q += partials[((long)b * 16 + i) * 2 + 1];
  }
  const float invN = 1.f / (float)(NTOKN * DIMN);
  float m = s * invN;
  float var = q * invN - m * m;
  stats[b * 2] = m;
  stats[b * 2 + 1] = rsqrtf(var + 1e-5f);
}

// ---------------- gemm_m1ln: 128x128 tile, 512 thr, LN2 fused into As staging, relu, bf16 out ----------------
__global__ __launch_bounds__(512) void gemm_m1ln(
    const unsigned short* __restrict__ X, const float* __restrict__ stats,
    const float* __restrict__ genc, const float* __restrict__ benc,
    const unsigned short* __restrict__ W, const float* __restrict__ bias,
    unsigned short* __restrict__ Y) {
  __shared__ unsigned short As[128 * 264];
  __shared__ unsigned short Bs[128 * 264];
  const int tid = threadIdx.x;
  const long m0 = (long)blockIdx.x * 128;
  const int n0 = blockIdx.y * 128;
  const int bb_ = (int)(m0 >> 10);
  const float mm = stats[bb_ * 2], inv = stats[bb_ * 2 + 1];
#pragma unroll
  for (int i = 0; i < 8; ++i) {
    int c = tid + i * 512;
    int row = c >> 5, seg = c & 31;
    long grow = m0 + row;
    int t = (int)(grow & 1023);
    ushort8 raw = *(const ushort8*)(X + grow * 256 + seg * 8);
    const float* gp = genc + (long)t * 256 + seg * 8;
    const float* bp = benc + (long)t * 256 + seg * 8;
    ushort8 y;
#pragma unroll
    for (int e = 0; e < 8; ++e)
      y[e] = f2b((b2f(raw[e]) - mm) * inv * gp[e] + bp[e]);
    *(ushort8*)&As[row * 264 + seg * 8] = y;
  }
#pragma unroll
  for (int i = 0; i < 8; ++i) {
    int c = tid + i * 512;
    int row = c >> 5, seg = c & 31;
    *(ushort8*)&Bs[row * 264 + seg * 8] = *(const ushort8*)(W + (long)(n0 + row) * 256 + seg * 8);
  }
  __syncthreads();
  const int wave = tid >> 6, lane = tid & 63;
  const int wr = wave >> 1, wc = wave & 1;
  const int lrow = lane & 15, kgrp = lane >> 4;
  f32x4 acc[2][4];
#pragma unroll
  for (int mt = 0; mt < 2; ++mt)
#pragma unroll
    for (int nt = 0; nt < 4; ++nt) acc[mt][nt] = f32x4{0.f, 0.f, 0.f, 0.f};
#pragma unroll
  for (int kc = 0; kc < 8; ++kc) {
    short8 af[2], bf[4];
#pragma unroll
    for (int mt = 0; mt < 2; ++mt)
      af[mt] = *(const short8*)&As[(wr * 32 + mt * 16 + lrow) * 264 + kc * 32 + kgrp * 8];
#pragma unroll
    for (int nt = 0; nt < 4; ++nt)
      bf[nt] = *(const short8*)&Bs[(wc * 64 + nt * 16 + lrow) * 264 + kc * 32 + kgrp * 8];
#pragma unroll
    for (int mt = 0; mt < 2; ++mt)
#pragma unroll
      for (int nt = 0; nt < 4; ++nt)
        acc[mt][nt] = __builtin_amdgcn_mfma_f32_16x16x32_bf16(af[mt], bf[nt], acc[mt][nt], 0, 0, 0);
  }
#pragma unroll
  for (int mt = 0; mt < 2; ++mt)
#pragma unroll
    for (int nt = 0; nt < 4; ++nt) {
      int n = n0 + wc * 64 + nt * 16 + lrow;
      float bn = bias[n];
#pragma unroll
      for (int r = 0; r < 4; ++r) {
        long m = m0 + wr * 32 + mt * 16 + kgrp * 4 + r;
        Y[m * 256 + n] = f2b(fmaxf(acc[mt][nt][r] + bn, 0.f));
      }
    }
}

// ---------------- gemm_tile<ACT,OUT>: 128x128 tile, 512 thr = 8 waves (4x2), K=256 one-shot ----------------
// OUT: 0 = bf16 out; 1 = fp32 out; 2 = fp32 out + fp32 residual
template <int ACT, int OUT>
__global__ __launch_bounds__(512) void gemm_tile(
    const unsigned short* __restrict__ X, const unsigned short* __restrict__ W,
    const float* __restrict__ bias, const float* __restrict__ res,
    void* __restrict__ Y, int Nfull) {
  __shared__ unsigned short As[128 * 264];
  __shared__ unsigned short Bs[128 * 264];
  const int tid = threadIdx.x;
  const long m0 = (long)blockIdx.x * 128;
  const int n0 = blockIdx.y * 128;
#pragma unroll
  for (int i = 0; i < 8; ++i) {
    int c = tid + i * 512;
    int row = c >> 5, seg = c & 31;
    *(ushort8*)&As[row * 264 + seg * 8] = *(const ushort8*)(X + (m0 + row) * 256 + seg * 8);
  }
#pragma unroll
  for (int i = 0; i < 8; ++i) {
    int c = tid + i * 512;
    int row = c >> 5, seg = c & 31;
    *(ushort8*)&Bs[row * 264 + seg * 8] = *(const ushort8*)(W + (long)(n0 + row) * 256 + seg * 8);
  }
  __syncthreads();
  const int wave = tid >> 6, lane = tid & 63;
  const int wr = wave >> 1, wc = wave & 1;
  const int lrow = lane & 15, kgrp = lane >> 4;
  f32x4 acc[2][4];
#pragma unroll
  for (int mt = 0; mt < 2; ++mt)
#pragma unroll
    for (int nt = 0; nt < 4; ++nt) acc[mt][nt] = f32x4{0.f, 0.f, 0.f, 0.f};
#pragma unroll
  for (int kc = 0; kc < 8; ++kc) {
    short8 af[2], bf[4];
#pragma unroll
    for (int mt = 0; mt < 2; ++mt)
      af[mt] = *(const short8*)&As[(wr * 32 + mt * 16 + lrow) * 264 + kc * 32 + kgrp * 8];
#pragma unroll
    for (int nt = 0; nt < 4; ++nt)
      bf[nt] = *(const short8*)&Bs[(wc * 64 + nt * 16 + lrow) * 264 + kc * 32 + kgrp * 8];
#pragma unroll
    for (int mt = 0; mt < 2; ++mt)
#pragma unroll
      for (int nt = 0; nt < 4; ++nt)
        acc[mt][nt] = __builtin_amdgcn_mfma_f32_16x16x32_bf16(af[mt], bf[nt], acc[mt][nt], 0, 0, 0);
  }
#pragma unroll
  for (int mt = 0; mt < 2; ++mt)
#pragma unroll
    for (int nt = 0; nt < 4; ++nt) {
      int n = n0 + wc * 64 + nt * 16 + lrow;
      float bn = bias[n];
#pragma unroll
      for (int r = 0; r < 4; ++r) {
        long m = m0 + wr * 32 + mt * 16 + kgrp * 4 + r;
        float v = acc[mt][nt][r] + bn;
        if (ACT) v = fmaxf(v, 0.f);
        if (OUT == 0)      ((unsigned short*)Y)[m * Nfull + n] = f2b(v);
        else if (OUT == 1) ((float*)Y)[m * Nfull + n] = v;
        else               ((float*)Y)[m * Nfull + n] = v + res[m * Nfull + n];
      }
    }
}

// ---------------- gemm_kv_tile: 512 thr, rowLN fused into A staging, K then V (Bs restaged) ----------------
__global__ __launch_bounds__(512) void gemm_kv_tile(
    const unsigned short* __restrict__ X,
    const float* __restrict__ gin, const float* __restrict__ bin,
    const unsigned short* __restrict__ Wk, const unsigned short* __restrict__ Wv,
    const float* __restrict__ bk, const float* __restrict__ bv,
    unsigned short* __restrict__ Kb, unsigned short* __restrict__ Vb) {
  __shared__ unsigned short As[128 * 264];
  __shared__ unsigned short Bs[128 * 264];
  const int tid = threadIdx.x;
  const long m0 = (long)blockIdx.x * 128;
  const int n0 = blockIdx.y * 128;
#pragma unroll
  for (int i = 0; i < 8; ++i) {
    int c = tid + i * 512;
    int row = c >> 5, seg = c & 31;
    ushort8 raw = *(const ushort8*)(X + (m0 + row) * 256 + seg * 8);
    float v[8];
    float s = 0.f, q = 0.f;
#pragma unroll
    for (int e = 0; e < 8; ++e) {
      v[e] = b2f(raw[e]);
      s += v[e]; q += v[e] * v[e];
    }
#pragma unroll
    for (int msk = 1; msk <= 16; msk <<= 1) {
      s += __shfl_xor(s, msk);
      q += __shfl_xor(q, msk);
    }
    float mean = s * (1.f / 256.f);
    float rinv = rsqrtf(q * (1.f / 256.f) - mean * mean + 1e-5f);
    const float* gp = gin + seg * 8;
    const float* bp = bin + seg * 8;
    ushort8 y;
#pragma unroll
    for (int e = 0; e < 8; ++e)
      y[e] = f2b((v[e] - mean) * rinv * gp[e] + bp[e]);
    *(ushort8*)&As[row * 264 + seg * 8] = y;
  }
  const int wave = tid >> 6, lane = tid & 63;
  const int wr = wave >> 1, wc = wave & 1;
  const int lrow = lane & 15, kgrp = lane >> 4;
  for (int which = 0; which < 2; ++which) {
    const unsigned short* W = which ? Wv : Wk;
    const float* bias = which ? bv : bk;
    unsigned short* Y = which ? Vb : Kb;
    if (which) __syncthreads();
#pragma unroll
    for (int i = 0; i < 8; ++i) {
      int c = tid + i * 512;
      int row = c >> 5, seg = c & 31;
      *(ushort8*)&Bs[row * 264 + seg * 8] = *(const ushort8*)(W + (long)(n0 + row) * 256 + seg * 8);
    }
    __syncthreads();
    f32x4 acc[2][4];
#pragma unroll
    for (int mt = 0; mt < 2; ++mt)
#pragma unroll
      for (int nt = 0; nt < 4; ++nt) acc[mt][nt] = f32x4{0.f, 0.f, 0.f, 0.f};
#pragma unroll
    for (int kc = 0; kc < 8; ++kc) {
      short8 af[2], bf[4];
#pragma unroll
      for (int mt = 0; mt < 2; ++mt)
        af[mt] = *(const short8*)&As[(wr * 32 + mt * 16 + lrow) * 264 + kc * 32 + kgrp * 8];
#pragma unroll
      for (int nt = 0; nt < 4; ++nt)
        bf[nt] = *(const short8*)&Bs[(wc * 64 + nt * 16 + lrow) * 264 + kc * 32 + kgrp * 8];
#pragma unroll
      for (int mt = 0; mt < 2; ++mt)
#pragma unroll
        for (int nt = 0; nt < 4; ++nt)
          acc[mt][nt] = __builtin_amdgcn_mfma_f32_16x16x32_bf16(af[mt], bf[nt], acc[mt][nt], 0, 0, 0);
    }
#pragma unroll
    for (int mt = 0; mt < 2; ++mt)
#pragma unroll
      for (int nt = 0; nt < 4; ++nt) {
        int n = n0 + wc * 64 + nt * 16 + lrow;
        float bn = bias[n];
#pragma unroll
        for (int r = 0; r < 4; ++r) {
          long m = m0 + wr * 32 + mt * 16 + kgrp * 4 + r;
          Y[m * 256 + n] = f2b(acc[mt][nt][r] + bn);
        }
      }
  }
}

// ---------------- gemm_tile64<ACT,OUT>: 64x128 tile for small-M GEMMs (256 thr) ----------------
template <int ACT, int OUT>
__global__ __launch_bounds__(256) void gemm_tile64(
    const unsigned short* __restrict__ X, const unsigned short* __restrict__ W,
    const float* __restrict__ bias, const float* __restrict__ res,
    void* __restrict__ Y, int Nfull) {
  __shared__ unsigned short As[64 * 264];
  __shared__ unsigned short Bs[128 * 264];
  const int tid = threadIdx.x;
  const long m0 = (long)blockIdx.x * 64;
  const int n0 = blockIdx.y * 128;
#pragma unroll
  for (int i = 0; i < 8; ++i) {
    int c = tid + i * 256;
    int row = c >> 5, seg = c & 31;
    *(ushort8*)&As[row * 264 + seg * 8] = *(const ushort8*)(X + (m0 + row) * 256 + seg * 8);
  }
#pragma unroll
  for (int i = 0; i < 16; ++i) {
    int c = tid + i * 256;
    int row = c >> 5, seg = c & 31;
    *(ushort8*)&Bs[row * 264 + seg * 8] = *(const ushort8*)(W + (long)(n0 + row) * 256 + seg * 8);
  }
  __syncthreads();
  const int wave = tid >> 6, lane = tid & 63;
  const int lrow = lane & 15, kgrp = lane >> 4;
  f32x4 acc[8];
#pragma unroll
  for (int nt = 0; nt < 8; ++nt) acc[nt] = f32x4{0.f, 0.f, 0.f, 0.f};
#pragma unroll
  for (int kc = 0; kc < 8; ++kc) {
    short8 af = *(const short8*)&As[(wave * 16 + lrow) * 264 + kc * 32 + kgrp * 8];
#pragma unroll
    for (int nt = 0; nt < 8; ++nt) {
      short8 bf = *(const short8*)&Bs[(nt * 16 + lrow) * 264 + kc * 32 + kgrp * 8];
      acc[nt] = __builtin_amdgcn_mfma_f32_16x16x32_bf16(af, bf, acc[nt], 0, 0, 0);
    }
  }
#pragma unroll
  for (int nt = 0; nt < 8; ++nt) {
    int n = n0 + nt * 16 + lrow;
    float bn = bias[n];
#pragma unroll
    for (int r = 0; r < 4; ++r) {
      long m = m0 + wave * 16 + kgrp * 4 + r;
      float v = acc[nt][r] + bn;
      if (ACT) v = fmaxf(v, 0.f);
      if (OUT == 0)      ((unsigned short*)Y)[m * Nfull + n] = f2b(v);
      else if (OUT == 1) ((float*)Y)[m * Nfull + n] = v;
      else               ((float*)Y)[m * Nfull + n] = v + res[m * Nfull + n];
    }
  }
}

// ---------------- gigh_tile: 512 thr, 128x128 tile, z selects gi/gh, fp32 out stride 768 ----------------
__global__ __launch_bounds__(512) void gigh_tile(
    const unsigned short* __restrict__ updb, const unsigned short* __restrict__ sbf,
    const unsigned short* __restrict__ Wih, const unsigned short* __restrict__ Whh,
    const float* __restrict__ bih, const float* __restrict__ bhh,
    float* __restrict__ gib, float* __restrict__ ghb) {
  const unsigned short* X = blockIdx.z ? sbf : updb;
  const unsigned short* W = blockIdx.z ? Whh : Wih;
  const float* bias = blockIdx.z ? bhh : bih;
  float* Y = blockIdx.z ? ghb : gib;
  __shared__ unsigned short As[128 * 264];
  __shared__ unsigned short Bs[128 * 264];
  const int tid = threadIdx.x;
  const long m0 = (long)blockIdx.x * 128;
  const int n0 = blockIdx.y * 128;
#pragma unroll
  for (int i = 0; i < 8; ++i) {
    int c = tid + i * 512;
    int row = c >> 5, seg = c & 31;
    *(ushort8*)&As[row * 264 + seg * 8] = *(const ushort8*)(X + (m0 + row) * 256 + seg * 8);
  }
#pragma unroll
  for (int i = 0; i < 8; ++i) {
    int c = tid + i * 512;
    int row = c >> 5, seg = c & 31;
    *(ushort8*)&Bs[row * 264 + seg * 8] = *(const ushort8*)(W + (long)(n0 + row) * 256 + seg * 8);
  }
  __syncthreads();
  const int wave = tid >> 6, lane = tid & 63;
  const int wr = wave >> 1, wc = wave & 1;
  const int lrow = lane & 15, kgrp = lane >> 4;
  f32x4 acc[2][4];
#pragma unroll
  for (int mt = 0; mt < 2; ++mt)
#pragma unroll
    for (int nt = 0; nt < 4; ++nt) acc[mt][nt] = f32x4{0.f, 0.f, 0.f, 0.f};
#pragma unroll
  for (int kc = 0; kc < 8; ++kc) {
    short8 af[2], bf[4];
#pragma unroll
    for (int mt = 0; mt < 2; ++mt)
      af[mt] = *(const short8*)&As[(wr * 32 + mt * 16 + lrow) * 264 + kc * 32 + kgrp * 8];
#pragma unroll
    for (int nt = 0; nt < 4; ++nt)
      bf[nt] = *(const short8*)&Bs[(wc * 64 + nt * 16 + lrow) * 264 + kc * 32 + kgrp * 8];
#pragma unroll
    for (int mt = 0; mt < 2; ++mt)
#pragma unroll
      for (int nt = 0; nt < 4; ++nt)
        acc[mt][nt] = __builtin_amdgcn_mfma_f32_16x16x32_bf16(af[mt], bf[nt], acc[mt][nt], 0, 0, 0);
  }
#pragma unroll
  for (int mt = 0; mt < 2; ++mt)
#pragma unroll
    for (int nt = 0; nt < 4; ++nt) {
      int n = n0 + wc * 64 + nt * 16 + lrow;
      float bn = bias[n];
#pragma unroll
      for (int r = 0; r < 4; ++r) {
        long m = m0 + wr * 32 + mt * 16 + kgrp * 4 + r;
        Y[m * 768 + n] = acc[mt][nt][r] + bn;
      }
    }
}

// ---------------- slots init ----------------
__global__ __launch_bounds__(256) void slots_init(const float* __restrict__ noise, const float* __restrict__ mu,
                                                  const float* __restrict__ sigma, float* __restrict__ slots) {
  long i = (long)blockIdx.x * 256 + threadIdx.x;
  int d = (int)(i & 255);
  slots[i] = mu[d] + sigma[d] * noise[i];
}

// ---------------- lnq_q: LN(slots) + q GEMM + slots->bf16, one block per batch ----------------
__global__ __launch_bounds__(256) void lnq_q(
    const float* __restrict__ slots, const float* __restrict__ gs, const float* __restrict__ bs,
    const unsigned short* __restrict__ Wq, const float* __restrict__ bq,
    unsigned short* __restrict__ qb, unsigned short* __restrict__ sbf) {
  __shared__ unsigned short S[16 * 264];
  const int b = blockIdx.x, tid = threadIdx.x;
  const int wave = tid >> 6, lane = tid & 63;
  for (int i = tid; i < 8 * 264; i += 256) S[8 * 264 + i] = 0;
#pragma unroll
  for (int rr = 0; rr < 2; ++rr) {
    int row = wave * 2 + rr;
    float4 xv = *(const float4*)(slots + ((long)b * 8 + row) * 256 + lane * 4);
    float s = xv.x + xv.y + xv.z + xv.w;
    float q = xv.x * xv.x + xv.y * xv.y + xv.z * xv.z + xv.w * xv.w;
    for (int off = 32; off; off >>= 1) { s += __shfl_xor(s, off); q += __shfl_xor(q, off); }
    float m = s * (1.f / 256.f);
    float inv = rsqrtf(q * (1.f / 256.f) - m * m + 1e-5f);
    float4 gv = *(const float4*)(gs + lane * 4);
    float4 bv = *(const float4*)(bs + lane * 4);
    ushort4v y, rb;
    y[0] = f2b((xv.x - m) * inv * gv.x + bv.x);
    y[1] = f2b((xv.y - m) * inv * gv.y + bv.y);
    y[2] = f2b((xv.z - m) * inv * gv.z + bv.z);
    y[3] = f2b((xv.w - m) * inv * gv.w + bv.w);
    rb[0] = f2b(xv.x); rb[1] = f2b(xv.y); rb[2] = f2b(xv.z); rb[3] = f2b(xv.w);
    *(ushort4v*)&S[row * 264 + lane * 4] = y;
    *(ushort4v*)(sbf + ((long)b * 8 + row) * 256 + lane * 4) = rb;
  }
  __syncthreads();
  const int lrow = lane & 15, kgrp = lane >> 4;
  short8 a[8];
#pragma unroll
  for (int kc = 0; kc < 8; ++kc)
    a[kc] = *(const short8*)&S[lrow * 264 + kc * 32 + kgrp * 8];
#pragma unroll
  for (int nt = 0; nt < 4; ++nt) {
    const int n = wave * 64 + nt * 16 + lrow;
    const unsigned short* wp = Wq + (long)n * 256 + kgrp * 8;
    f32x4 acc = {0.f, 0.f, 0.f, 0.f};
#pragma unroll
    for (int kc = 0; kc < 8; ++kc)
      acc = __builtin_amdgcn_mfma_f32_16x16x32_bf16(a[kc], *(const short8*)(wp + kc * 32), acc, 0, 0, 0);
    if (kgrp < 2) {
      float bn = bq[n];
#pragma unroll
      for (int r = 0; r < 4; ++r)
        qb[((long)b * 8 + kgrp * 4 + r) * 256 + n] = f2b(acc[r] + bn);
    }
  }
}

// ---------------- attn1b: MFMA dots + wave-parallel softmax + asum/upd partials (bf16 partials) ----------------
__global__ __launch_bounds__(256) void attn1b(
    const unsigned short* __restrict__ qb, const unsigned short* __restrict__ Kb,
    const unsigned short* __restrict__ Vb,
    unsigned short* __restrict__ upd_part, float* __restrict__ asum_part) {
  __shared__ unsigned short Ks[64 * 264];
  __shared__ unsigned short Qs[16 * 264];
  __shared__ float attnS[64 * 8];
  __shared__ float red[4 * 2048];
  const int jt = blockIdx.x, b = blockIdx.y, tid = threadIdx.x;
  const int wave = tid >> 6, lane = tid & 63;
#pragma unroll
  for (int i = 0; i < 8; ++i) {
    int c = tid + i * 256;
    int row = c >> 5, seg = c & 31;
    *(ushort8*)&Ks[row * 264 + seg * 8] =
        *(const ushort8*)(Kb + ((long)(b * NTOKN + jt * 64 + row)) * 256 + seg * 8);
  }
  {
    int row = tid >> 5, seg = tid & 31;
    *(ushort8*)&Qs[row * 264 + seg * 8] = *(const ushort8*)(qb + ((long)(b * 8 + row)) * 256 + seg * 8);
  }
  for (int i = tid; i < 8 * 264; i += 256) Qs[8 * 264 + i] = 0;
  __syncthreads();
  const int lrow = lane & 15, kgrp = lane >> 4;
  f32x4 acc = {0.f, 0.f, 0.f, 0.f};
#pragma unroll
  for (int kc = 0; kc < 8; ++kc) {
    short8 af = *(const short8*)&Ks[(wave * 16 + lrow) * 264 + kc * 32 + kgrp * 8];
    short8 qf = *(const short8*)&Qs[lrow * 264 + kc * 32 + kgrp * 8];
    acc = __builtin_amdgcn_mfma_f32_16x16x32_bf16(af, qf, acc, 0, 0, 0);
  }
  float t0[4], mx[4], e[4], sm[4];
#pragma unroll
  for (int r = 0; r < 4; ++r) { t0[r] = acc[r] * SCALEF; mx[r] = t0[r]; }
#pragma unroll
  for (int msk = 1; msk <= 4; msk <<= 1)
#pragma unroll
    for (int r = 0; r < 4; ++r) mx[r] = fmaxf(mx[r], __shfl_xor(mx[r], msk));
#pragma unroll
  for (int r = 0; r < 4; ++r) { e[r] = expf(t0[r] - mx[r]); sm[r] = e[r]; }
#pragma unroll
  for (int msk = 1; msk <= 4; msk <<= 1)
#pragma unroll
    for (int r = 0; r < 4; ++r) sm[r] += __shfl_xor(sm[r], msk);
  if (lrow < 8) {
#pragma unroll
    for (int r = 0; r < 4; ++r) {
      int jl = wave * 16 + kgrp * 4 + r;
      attnS[jl * 8 + lrow] = e[r] / sm[r] + 1e-8f;
    }
  }
  __syncthreads();
  {
    int s0 = wave * 2;
    float v0 = attnS[lane * 8 + s0], v1 = attnS[lane * 8 + s0 + 1];
    for (int off = 32; off; off >>= 1) { v0 += __shfl_xor(v0, off); v1 += __shfl_xor(v1, off); }
    if (lane == 0) {
      asum_part[((long)(b * 16 + jt)) * 8 + s0] = v0;
      asum_part[((long)(b * 16 + jt)) * 8 + s0 + 1] = v1;
    }
  }
  float au[8][4] = {};
  for (int jl = 0; jl < 16; ++jl) {
    int j = wave * 16 + jl;
    ushort4v v4 = *(const ushort4v*)(Vb + ((long)(b * NTOKN + jt * 64 + j)) * 256 + lane * 4);
    float v0 = b2f(v4[0]), v1 = b2f(v4[1]), v2 = b2f(v4[2]), v3 = b2f(v4[3]);
    float4 a01 = *(const float4*)&attnS[j * 8];
    float4 a23 = *(const float4*)&attnS[j * 8 + 4];
    float aw[8] = {a01.x, a01.y, a01.z, a01.w, a23.x, a23.y, a23.z, a23.w};
#pragma unroll
    for (int s = 0; s < 8; ++s) {
      au[s][0] += aw[s] * v0; au[s][1] += aw[s] * v1;
      au[s][2] += aw[s] * v2; au[s][3] += aw[s] * v3;
    }
  }
#pragma unroll
  for (int s = 0; s < 8; ++s)
    *(float4*)&red[wave * 2048 + s * 256 + lane * 4] = make_float4(au[s][0], au[s][1], au[s][2], au[s][3]);
  __syncthreads();
#pragma unroll
  for (int i = 0; i < 8; ++i) {
    int idx = tid + i * 256;
    float sum = red[idx] + red[2048 + idx] + red[4096 + idx] + red[6144 + idx];
    upd_part[((long)(b * 16 + jt)) * 2048 + idx] = f2b(sum);
  }
}

// ---------------- upd_reduce (bf16 partials in) ----------------
__global__ __launch_bounds__(256) void upd_reduce(
    const unsigned short* __restrict__ upd_part, const float* __restrict__ asum_part,
    unsigned short* __restrict__ updb) {
  const int bx = blockIdx.x;
  const int b = bx >> 3, s = bx & 7;
  const int tid = threadIdx.x;
  float as = 0.f;
#pragma unroll
  for (int jt = 0; jt < 16; ++jt) as += asum_part[((long)(b * 16 + jt)) * 8 + s];
  float sum = 0.f;
#pragma unroll
  for (int jt = 0; jt < 16; ++jt)
    sum += b2f(upd_part[((long)(b * 16 + jt)) * 2048 + s * 256 + tid]);
  updb[((long)b * 8 + s) * 256 + tid] = f2b(sum / as);
}

// ---------------- GRU gates + LN(g_ff) fused ----------------
__global__ __launch_bounds__(256) void gru_ln(const float* __restrict__ gi, const float* __restrict__ gh,
                                              const float* __restrict__ slots,
                                              const float* __restrict__ gff, const float* __restrict__ bff,
                                              float* __restrict__ ns, unsigned short* __restrict__ ffl) {
  const int tid = threadIdx.x, lane = tid & 63;
  const long row = (long)blockIdx.x * 4 + (tid >> 6);
  const int d = lane * 4;
  float4 i1 = *(const float4*)(gi + row * 768 + d);
  float4 i2 = *(const float4*)(gi + row * 768 + 256 + d);
  float4 i3 = *(const float4*)(gi + row * 768 + 512 + d);
  float4 h1 = *(const float4*)(gh + row * 768 + d);
  float4 h2 = *(const float4*)(gh + row * 768 + 256 + d);
  float4 h3 = *(const float4*)(gh + row * 768 + 512 + d);
  float4 sl = *(const float4*)(slots + row * 256 + d);
  float n4[4];
  float r, z, nn;
  r = 1.f / (1.f + expf(-(i1.x + h1.x))); z = 1.f / (1.f + expf(-(i2.x + h2.x)));
  nn = tanhf(i3.x + r * h3.x); n4[0] = (1.f - z) * nn + z * sl.x;
  r = 1.f / (1.f + expf(-(i1.y + h1.y))); z = 1.f / (1.f + expf(-(i2.y + h2.y)));
  nn = tanhf(i3.y + r * h3.y); n4[1] = (1.f - z) * nn + z * sl.y;
  r = 1.f / (1.f + expf(-(i1.z + h1.z))); z = 1.f / (1.f + expf(-(i2.z + h2.z)));
  nn = tanhf(i3.z + r * h3.z); n4[2] = (1.f - z) * nn + z * sl.z;
  r = 1.f / (1.f + expf(-(i1.w + h1.w))); z = 1.f / (1.f + expf(-(i2.w + h2.w)));
  nn = tanhf(i3.w + r * h3.w); n4[3] = (1.f - z) * nn + z * sl.w;
  *(float4*)(ns + row * 256 + d) = make_float4(n4[0], n4[1], n4[2], n4[3]);
  float s = n4[0] + n4[1] + n4[2] + n4[3];
  float q = n4[0] * n4[0] + n4[1] * n4[1] + n4[2] * n4[2] + n4[3] * n4[3];
  for (int off = 32; off; off >>= 1) { s += __shfl_xor(s, off); q += __shfl_xor(q, off); }
  float m = s * (1.f / 256.f);
  float inv = rsqrtf(q * (1.f / 256.f) - m * m + 1e-5f);
  float4 gv = *(const float4*)(gff + d);
  float4 bv = *(const float4*)(bff + d);
  ushort4v y;
  y[0] = f2b((n4[0] - m) * inv * gv.x + bv.x);
  y[1] = f2b((n4[1] - m) * inv * gv.y + bv.y);
  y[2] = f2b((n4[2] - m) * inv * gv.z + bv.z);
  y[3] = f2b((n4[3] - m) * inv * gv.w + bv.w);
  *(ushort4v*)(ffl + row * 256 + d) = y;
}

// ---------------- output ----------------
__global__ __launch_bounds__(256) void write_out(const float* __restrict__ slots, const int* __restrict__ flag,
                                                 void* __restrict__ out) {
  long i = (long)blockIdx.x * 256 + threadIdx.x;
  float v = slots[i];
  if (*flag) ((__hip_bfloat16*)out)[i] = __float2bfloat16(v);
  else ((float*)out)[i] = v;
}

// ---------------- host ----------------
extern "C" void kernel_launch(void* const* d_in, const int* in_sizes, int n_in,
                              void* d_out, int out_size, void* d_ws, size_t ws_size,
                              hipStream_t stream) {
  (void)in_sizes; (void)n_in; (void)out_size; (void)ws_size;
  float* wsf = (float*)d_ws;
  long o = 0;
  float* conv = wsf; o += kConvTotal;
  unsigned short* wbf = (unsigned short*)(wsf + o); o += kWTotal / 2;
  unsigned short* A   = (unsigned short*)(wsf + o); o += (long)BB * NTOKN * DIMN / 2;
  unsigned short* X1  = (unsigned short*)(wsf + o); o += (long)BB * NTOKN * DIMN / 2;
  unsigned short* X2  = (unsigned short*)(wsf + o); o += (long)BB * NTOKN * DIMN / 2;
  unsigned short* Kb  = (unsigned short*)(wsf + o); o += (long)BB * NTOKN * DIMN / 2;
  unsigned short* Vb  = (unsigned short*)(wsf + o); o += (long)BB * NTOKN * DIMN / 2;
  float* slots = wsf + o; o += 131072;
  unsigned short* sbf = (unsigned short*)(wsf + o); o += 65536;
  unsigned short* qb  = (unsigned short*)(wsf + o); o += 65536;
  unsigned short* upd_part = (unsigned short*)(wsf + o); o += 1048576;  // [64][16][8][256] bf16
  float* asum_part = wsf + o; o += 8192;
  unsigned short* updb = (unsigned short*)(wsf + o); o += 65536;
  float* gib   = wsf + o; o += 393216;
  float* ghb   = wsf + o; o += 393216;
  float* nsb   = wsf + o; o += 131072;
  unsigned short* ffl  = (unsigned short*)(wsf + o); o += 65536;
  unsigned short* hbuf = (unsigned short*)(wsf + o); o += 65536;
  float* partials = wsf + o; o += 2048;
  float* stats = wsf + o; o += 128;
  int* flag = (int*)(wsf + o); o += 16;

  long coff[kNConv];
  { long acc = 0; for (int i = 0; i < kNConv; ++i) { coff[i] = acc; acc += kConvSizes[i]; } }
  const float* noise_f = conv + coff[0];
  const float* Wpos = conv + coff[1];
  const float* bpos = conv + coff[2];
  const float* genc = conv + coff[3];
  const float* benc = conv + coff[4];
  const float* bm1  = conv + coff[6];
  const float* bm2  = conv + coff[8];
  const float* gin  = conv + coff[9];
  const float* bin  = conv + coff[10];
  const float* bq   = conv + coff[12];
  const float* bk   = conv + coff[14];
  const float* bv   = conv + coff[16];
  const float* bih  = conv + coff[19];
  const float* bhh  = conv + coff[20];
  const float* gs   = conv + coff[21];
  const float* bs   = conv + coff[22];
  const float* gff  = conv + coff[23];
  const float* bff  = conv + coff[24];
  const float* bf1  = conv + coff[26];
  const float* bf2  = conv + coff[28];
  const float* mu   = conv + coff[29];
  const float* sigma = conv + coff[30];

  const unsigned short* Wm1b = wbf;
  const unsigned short* Wm2b = wbf + 65536;
  const unsigned short* Wqb  = wbf + 131072;
  const unsigned short* Wkb  = wbf + 196608;
  const unsigned short* Wvb  = wbf + 262144;
  const unsigned short* Wihb = wbf + 327680;
  const unsigned short* Whhb = wbf + 524288;
  const unsigned short* Wf1b = wbf + 720896;
  const unsigned short* Wf2b = wbf + 786432;

  detect_dtype<<<1, 1, 0, stream>>>(d_in[10], flag);

  PtrPack pk;
  for (int i = 0; i < kNConv; ++i) pk.p[i] = d_in[i + 1];
  convert_weights<<<(kConvTotal + 255) / 256, 256, 0, stream>>>(pk, flag, conv);
  convert_wbf16<<<(kWTotal + 255) / 256, 256, 0, stream>>>(conv, wbf);

  // encoder
  posembed_stats<<<dim3(16, 64), 256, 0, stream>>>(d_in[0], flag, Wpos, bpos, A, partials);
  stats_reduce<<<1, 64, 0, stream>>>(partials, stats);
  const int MT = BB * NTOKN / 128;  // 512 m-tiles
  gemm_m1ln<<<dim3(MT, 2), 512, 0, stream>>>(A, stats, genc, benc, Wm1b, bm1, X1);
  gemm_tile<1, 0><<<dim3(MT, 2), 512, 0, stream>>>(X1, Wm2b, bm2, nullptr, X2, 256);
  gemm_kv_tile<<<dim3(MT, 2), 512, 0, stream>>>(X2, gin, bin, Wkb, Wvb, bk, bv, Kb, Vb);

  slots_init<<<512, 256, 0, stream>>>(noise_f, mu, sigma, slots);

  for (int it = 0; it < NSTEP; ++it) {
    lnq_q<<<64, 256, 0, stream>>>(slots, gs, bs, Wqb, bq, qb, sbf);
    attn1b<<<dim3(16, 64), 256, 0, stream>>>(qb, Kb, Vb, upd_part, asum_part);
    upd_reduce<<<512, 256, 0, stream>>>(upd_part, asum_part, updb);
    gigh_tile<<<dim3(4, 6, 2), 512, 0, stream>>>(updb, sbf, Wihb, Whhb, bih, bhh, gib, ghb);
    gru_ln<<<128, 256, 0, stream>>>(gib, ghb, slots, gff, bff, nsb, ffl);
    gemm_tile64<1, 0><<<dim3(8, 2), 256, 0, stream>>>(ffl, Wf1b, bf1, nullptr, hbuf, 256);
    gemm_tile64<0, 2><<<dim3(8, 2), 256, 0, stream>>>(hbuf, Wf2b, bf2, nsb, slots, 256);
  }

  write_out<<<512, 256, 0, stream>>>(slots, flag, d_out);
}